// Round 10
// baseline (330.410 us; speedup 1.0000x reference)
//
#include <hip/hip_runtime.h>
#include <cstddef>
#include <cstdint>

#define IN_DIM 256
#define H_DIM  128
#define C_DIM  40
#define BM     128
#define LDQ    68    // ushort stride of quarter-slab rows (136 B; 2-bank spread)
#define XA_C   32    // split-x: xa cols -> 64-B rows, 64-B aligned, ONE line/gather
#define XB_C   8     // split-x: xb cols -> 16-B rows, 1.6 MB, L2-resident
#define STEP   512   // ushorts per ks slab of b_frag/w2f: 64 lanes x 8 bf16

typedef short bf16x8 __attribute__((ext_vector_type(8)));
typedef float f32x16 __attribute__((ext_vector_type(16)));
typedef uint  u32x4  __attribute__((ext_vector_type(4)));

__device__ __forceinline__ ushort f2bf(float f) {   // RNE fp32 -> bf16
  uint u = __builtin_bit_cast(uint, f);
  u += 0x7fffu + ((u >> 16) & 1u);
  return (ushort)(u >> 16);
}
__device__ __forceinline__ float bf2f(uint s) {     // low 16 bits -> f32
  uint u = s << 16;
  return __builtin_bit_cast(float, u);
}
// packed fp32x2 -> bf16x2 (HW cvt if available; manual RNE fallback)
__device__ __forceinline__ uint pack2bf(float a, float b) {
#if __has_builtin(__builtin_amdgcn_cvt_pk_bf16_f32)
  typedef __bf16 bf16v2 __attribute__((ext_vector_type(2)));
  bf16v2 r = __builtin_amdgcn_cvt_pk_bf16_f32(a, b);
  return __builtin_bit_cast(uint, r);
#else
  return (uint)f2bf(a) | ((uint)f2bf(b) << 16);
#endif
}

// ---------------------------------------------------------------------------
// Setup (one launch):
//  tid < E:     CSR row_ptr via boundary scan of sorted dst (coalesced O(E)).
//  next 4096:   W1 -> b_frag (MFMA B-fragment order for GEMM1).
//  next 1024:   W2 -> w2f   (MFMA B-fragment order for GEMM2, zero-pad n>=40).
// ---------------------------------------------------------------------------
__global__ void setup_kernel(const int* __restrict__ dst, int E,
                             int* __restrict__ row_ptr, int N,
                             const float* __restrict__ W1,
                             const float* __restrict__ W2,
                             ushort* __restrict__ b_frag,
                             ushort* __restrict__ w2f) {
  int tid = blockIdx.x * blockDim.x + threadIdx.x;
  if (tid < E) {
    int d1 = dst[tid];
    int d0 = (tid == 0) ? -1 : dst[tid - 1];
    for (int v = d0 + 1; v <= d1; ++v) row_ptr[v] = tid;
    if (tid == E - 1)
      for (int v = d1 + 1; v <= N; ++v) row_ptr[v] = E;
    return;
  }
  int u = tid - E;
  if (u < 4096) {                               // W1 -> b_frag fragment order
    int l = u & 63, ks = (u >> 6) & 15, tn = u >> 10;
    int n  = 32 * tn + (l & 31);
    int k0 = ks * 16 + ((l >> 5) << 3);
    ushort r[8];
#pragma unroll
    for (int j = 0; j < 8; ++j) r[j] = f2bf(W1[(k0 + j) * H_DIM + n]);
    *(uint4*)(b_frag + u * 8) = *(uint4*)r;
    return;
  }
  u -= 4096;
  if (u < 1024) {                               // W2 -> w2f fragment order
    int l = u & 63, kt = u >> 6;                // kt = kb*2 + tn
    int tn = kt & 1, kb = kt >> 1;
    int n  = 32 * tn + (l & 31);
    int k0 = kb * 16 + ((l >> 5) << 3);
    ushort r[8];
#pragma unroll
    for (int j = 0; j < 8; ++j)
      r[j] = (n < C_DIM) ? f2bf(W2[(k0 + j) * C_DIM + n]) : (ushort)0;
    *(uint4*)(w2f + u * 8) = *(uint4*)r;
  }
}

// ---------------------------------------------------------------------------
// Fused dense MLP -> split z0 (z0a [N][32] bf16 + z0b [N][8] bf16).
// R9 structure (quarter-slab, zero barriers, continuous staging issue);
// ONLY the final store changed to the split layout required by spmm.
// ---------------------------------------------------------------------------
__global__ __launch_bounds__(256, 4) void fused_dense_kernel(
    const float* __restrict__ feat, const ushort* __restrict__ b_frag,
    const ushort* __restrict__ w2f, ushort* __restrict__ z0a,
    ushort* __restrict__ z0b, int N) {
  __shared__ __align__(16) ushort smem[4 * 32 * LDQ];   // 17408 B

  const int t = threadIdx.x;
  const int w = t >> 6, l = t & 63;
  const int nb = blockIdx.x * BM;
  ushort* slab = smem + w * (32 * LDQ);          // this wave's private region

  const int sr = l >> 4;                          // staging row-in-group 0..3
  const int sc = l & 15;                          // staging col quad (16 B)

  f32x16 acc[4];
#pragma unroll
  for (int tn = 0; tn < 4; ++tn)
#pragma unroll
    for (int r = 0; r < 16; ++r) acc[tn][r] = 0.f;

  const ushort* bp = b_frag + l * 8;
  bf16x8 Bx[2][4];
#pragma unroll
  for (int tn = 0; tn < 4; ++tn)
    Bx[0][tn] = *(const bf16x8*)(bp + tn * (16 * STEP));

  const float* fbase = feat + (size_t)(nb + 32 * w) * IN_DIM + sc * 4;

  float4 pre[8];
#pragma unroll
  for (int c = 0; c < 8; ++c) {
    int grow = nb + 32 * w + 4 * c + sr;
    const float* p = fbase + (size_t)(4 * c + sr) * IN_DIM;
    if (grow >= N) p = feat + (size_t)(N - 1) * IN_DIM + sc * 4;
    pre[c] = *(const float4*)(p);
  }
#pragma unroll
  for (int c = 0; c < 8; ++c) {
    uint2 pk;
    pk.x = pack2bf(pre[c].x, pre[c].y);
    pk.y = pack2bf(pre[c].z, pre[c].w);
    *(uint2*)(slab + (4 * c + sr) * LDQ + sc * 4) = pk;
  }

  const ushort* Abase = slab + (l & 31) * LDQ + ((l >> 5) << 3);

#pragma unroll
  for (int q = 0; q < 4; ++q) {
#pragma unroll
    for (int ks = 0; ks < 4; ++ks) {
      const int gks = 4 * q + ks;
      const int c = gks & 1;
      if (gks < 15) {
#pragma unroll
        for (int tn = 0; tn < 4; ++tn)
          Bx[c ^ 1][tn] = *(const bf16x8*)(bp + tn * (16 * STEP) + (gks + 1) * STEP);
      }
      if (q < 3) {
#pragma unroll
        for (int d = 0; d < 2; ++d) {
          const int cc = 2 * ks + d;
          int grow = nb + 32 * w + 4 * cc + sr;
          const float* p = fbase + (size_t)(4 * cc + sr) * IN_DIM + (q + 1) * 64;
          if (grow >= N) p = feat + (size_t)(N - 1) * IN_DIM + sc * 4 + (q + 1) * 64;
          pre[cc] = *(const float4*)(p);
        }
      }
      bf16x8 af = *(const bf16x8*)(Abase + ks * 16);
#pragma unroll
      for (int tn = 0; tn < 4; ++tn)
        acc[tn] = __builtin_amdgcn_mfma_f32_32x32x16_bf16(af, Bx[c][tn], acc[tn], 0, 0, 0);
    }
    if (q < 3) {
#pragma unroll
      for (int c = 0; c < 8; ++c) {
        uint2 pk;
        pk.x = pack2bf(pre[c].x, pre[c].y);
        pk.y = pack2bf(pre[c].z, pre[c].w);
        *(uint2*)(slab + (4 * c + sr) * LDQ + sc * 4) = pk;
      }
    }
  }

  // ---- GEMM2 over two h-chunks reusing the quarter slab (zero barriers)
  f32x16 acc2[2];
#pragma unroll
  for (int tn = 0; tn < 2; ++tn)
#pragma unroll
    for (int r = 0; r < 16; ++r) acc2[tn][r] = 0.f;

  const ushort* Hbase = slab + (l & 31) * LDQ + ((l >> 5) << 3);
  const ushort* wp = w2f + l * 8;

#pragma unroll
  for (int hc = 0; hc < 2; ++hc) {
#pragma unroll
    for (int tn = 2 * hc; tn < 2 * hc + 2; ++tn) {
      int col = (tn - 2 * hc) * 32 + (l & 31);
#pragma unroll
      for (int r = 0; r < 16; ++r) {
        int nl = (r & 3) + 8 * (r >> 2) + 4 * (l >> 5);
        float v = acc[tn][r];
        slab[nl * LDQ + col] = f2bf(v > 0.f ? v : 0.f);
      }
    }
#pragma unroll
    for (int kb = 4 * hc; kb < 4 * hc + 4; ++kb) {
      bf16x8 af = *(const bf16x8*)(Hbase + (kb - 4 * hc) * 16);
#pragma unroll
      for (int tn = 0; tn < 2; ++tn) {
        bf16x8 bfr = *(const bf16x8*)(wp + (kb * 2 + tn) * STEP);
        acc2[tn] = __builtin_amdgcn_mfma_f32_32x32x16_bf16(af, bfr, acc2[tn], 0, 0, 0);
      }
    }
  }

  // ---- store split z0: cols 0..31 -> z0a, cols 32..39 -> z0b
#pragma unroll
  for (int r = 0; r < 16; ++r) {
    int node = nb + 32 * w + (r & 3) + 8 * (r >> 2) + 4 * (l >> 5);
    if (node < N) {
      z0a[(size_t)node * XA_C + (l & 31)] = f2bf(acc2[0][r]);
      if ((l & 31) < XB_C)
        z0b[(size_t)node * XB_C + (l & 31)] = f2bf(acc2[1][r]);
    }
  }
}

// ---------------------------------------------------------------------------
// SPMM (CSR, dst-sorted), split-x done right. One wave per node.
// lane = 4*h + j: h = edge slot 0..15, j = col quad 0..3.
// xa [N][32] bf16: 64-B, 64-B-aligned rows -> ONE cacheline per gathered row;
//   a gather instruction covers 16 edges with 16 fully-used lines and ALL 64
//   lanes active (vs old 8 edges / 16 half-used lines / 40 active lanes).
// xb [N][8] bf16: 16-B rows, 1.6 MB -> L2-resident; handled by the j==0 lane
//   group (one exec-masked load per group, no per-lane pointer select).
// Reduce over h = lane bits 2..5 (shfl_xor 4,8,16,32); partners share j.
// ---------------------------------------------------------------------------
__global__ __launch_bounds__(256) void spmm_kernel(
    const int* __restrict__ row_ptr, const int* __restrict__ esrc,
    const float* __restrict__ eval, const ushort* __restrict__ xa,
    const ushort* __restrict__ xb, ushort* __restrict__ za,
    ushort* __restrict__ zb8, float* __restrict__ zf, int N, int out_f32) {
  int node = (blockIdx.x << 2) + (threadIdx.x >> 6);
  if (node >= N) return;
  const int lane = threadIdx.x & 63;
  const int h = lane >> 2;          // edge slot 0..15
  const int j = lane & 3;           // col quad: cols 8j..8j+7 of xa

  int e   = row_ptr[node];
  int end = row_ptr[node + 1];

  float acc[8], accb[8];
#pragma unroll
  for (int c = 0; c < 8; ++c) { acc[c] = 0.f; accb[c] = 0.f; }

  // 32 edges per iteration: two independent 16-edge gather chains
  for (; e + 32 <= end; e += 32) {
    int   s0 = esrc[e + h];
    int   s1 = esrc[e + 16 + h];
    float v0 = eval[e + h];
    float v1 = eval[e + 16 + h];
    u32x4 a = *(const u32x4*)(xa + (size_t)s0 * XA_C + j * 8);
    u32x4 b = *(const u32x4*)(xa + (size_t)s1 * XA_C + j * 8);
    acc[0] = fmaf(v0, bf2f(a.x & 0xffffu), acc[0]);
    acc[1] = fmaf(v0, bf2f(a.x >> 16),     acc[1]);
    acc[2] = fmaf(v0, bf2f(a.y & 0xffffu), acc[2]);
    acc[3] = fmaf(v0, bf2f(a.y >> 16),     acc[3]);
    acc[4] = fmaf(v0, bf2f(a.z & 0xffffu), acc[4]);
    acc[5] = fmaf(v0, bf2f(a.z >> 16),     acc[5]);
    acc[6] = fmaf(v0, bf2f(a.w & 0xffffu), acc[6]);
    acc[7] = fmaf(v0, bf2f(a.w >> 16),     acc[7]);
    acc[0] = fmaf(v1, bf2f(b.x & 0xffffu), acc[0]);
    acc[1] = fmaf(v1, bf2f(b.x >> 16),     acc[1]);
    acc[2] = fmaf(v1, bf2f(b.y & 0xffffu), acc[2]);
    acc[3] = fmaf(v1, bf2f(b.y >> 16),     acc[3]);
    acc[4] = fmaf(v1, bf2f(b.z & 0xffffu), acc[4]);
    acc[5] = fmaf(v1, bf2f(b.z >> 16),     acc[5]);
    acc[6] = fmaf(v1, bf2f(b.w & 0xffffu), acc[6]);
    acc[7] = fmaf(v1, bf2f(b.w >> 16),     acc[7]);
    if (j == 0) {
      u32x4 p = *(const u32x4*)(xb + (size_t)s0 * XB_C);
      u32x4 q = *(const u32x4*)(xb + (size_t)s1 * XB_C);
      accb[0] = fmaf(v0, bf2f(p.x & 0xffffu), accb[0]);
      accb[1] = fmaf(v0, bf2f(p.x >> 16),     accb[1]);
      accb[2] = fmaf(v0, bf2f(p.y & 0xffffu), accb[2]);
      accb[3] = fmaf(v0, bf2f(p.y >> 16),     accb[3]);
      accb[4] = fmaf(v0, bf2f(p.z & 0xffffu), accb[4]);
      accb[5] = fmaf(v0, bf2f(p.z >> 16),     accb[5]);
      accb[6] = fmaf(v0, bf2f(p.w & 0xffffu), accb[6]);
      accb[7] = fmaf(v0, bf2f(p.w >> 16),     accb[7]);
      accb[0] = fmaf(v1, bf2f(q.x & 0xffffu), accb[0]);
      accb[1] = fmaf(v1, bf2f(q.x >> 16),     accb[1]);
      accb[2] = fmaf(v1, bf2f(q.y & 0xffffu), accb[2]);
      accb[3] = fmaf(v1, bf2f(q.y >> 16),     accb[3]);
      accb[4] = fmaf(v1, bf2f(q.z & 0xffffu), accb[4]);
      accb[5] = fmaf(v1, bf2f(q.z >> 16),     accb[5]);
      accb[6] = fmaf(v1, bf2f(q.w & 0xffffu), accb[6]);
      accb[7] = fmaf(v1, bf2f(q.w >> 16),     accb[7]);
    }
  }
  for (; e + 16 <= end; e += 16) {
    int   s = esrc[e + h];
    float v = eval[e + h];
    u32x4 a = *(const u32x4*)(xa + (size_t)s * XA_C + j * 8);
    acc[0] = fmaf(v, bf2f(a.x & 0xffffu), acc[0]);
    acc[1] = fmaf(v, bf2f(a.x >> 16),     acc[1]);
    acc[2] = fmaf(v, bf2f(a.y & 0xffffu), acc[2]);
    acc[3] = fmaf(v, bf2f(a.y >> 16),     acc[3]);
    acc[4] = fmaf(v, bf2f(a.z & 0xffffu), acc[4]);
    acc[5] = fmaf(v, bf2f(a.z >> 16),     acc[5]);
    acc[6] = fmaf(v, bf2f(a.w & 0xffffu), acc[6]);
    acc[7] = fmaf(v, bf2f(a.w >> 16),     acc[7]);
    if (j == 0) {
      u32x4 p = *(const u32x4*)(xb + (size_t)s * XB_C);
      accb[0] = fmaf(v, bf2f(p.x & 0xffffu), accb[0]);
      accb[1] = fmaf(v, bf2f(p.x >> 16),     accb[1]);
      accb[2] = fmaf(v, bf2f(p.y & 0xffffu), accb[2]);
      accb[3] = fmaf(v, bf2f(p.y >> 16),     accb[3]);
      accb[4] = fmaf(v, bf2f(p.z & 0xffffu), accb[4]);
      accb[5] = fmaf(v, bf2f(p.z >> 16),     accb[5]);
      accb[6] = fmaf(v, bf2f(p.w & 0xffffu), accb[6]);
      accb[7] = fmaf(v, bf2f(p.w >> 16),     accb[7]);
    }
  }
  if (e < end) {                    // tail: clamp slots past the end, weight 0
    int ei = e + h;
    int ec = ei < end ? ei : end - 1;
    int   s  = esrc[ec];
    float v0 = eval[ec];
    float v  = ei < end ? v0 : 0.f;
    u32x4 a = *(const u32x4*)(xa + (size_t)s * XA_C + j * 8);
    acc[0] = fmaf(v, bf2f(a.x & 0xffffu), acc[0]);
    acc[1] = fmaf(v, bf2f(a.x >> 16),     acc[1]);
    acc[2] = fmaf(v, bf2f(a.y & 0xffffu), acc[2]);
    acc[3] = fmaf(v, bf2f(a.y >> 16),     acc[3]);
    acc[4] = fmaf(v, bf2f(a.z & 0xffffu), acc[4]);
    acc[5] = fmaf(v, bf2f(a.z >> 16),     acc[5]);
    acc[6] = fmaf(v, bf2f(a.w & 0xffffu), acc[6]);
    acc[7] = fmaf(v, bf2f(a.w >> 16),     acc[7]);
    if (j == 0) {
      u32x4 p = *(const u32x4*)(xb + (size_t)s * XB_C);
      accb[0] = fmaf(v, bf2f(p.x & 0xffffu), accb[0]);
      accb[1] = fmaf(v, bf2f(p.x >> 16),     accb[1]);
      accb[2] = fmaf(v, bf2f(p.y & 0xffffu), accb[2]);
      accb[3] = fmaf(v, bf2f(p.y >> 16),     accb[3]);
      accb[4] = fmaf(v, bf2f(p.z & 0xffffu), accb[4]);
      accb[5] = fmaf(v, bf2f(p.z >> 16),     accb[5]);
      accb[6] = fmaf(v, bf2f(p.w & 0xffffu), accb[6]);
      accb[7] = fmaf(v, bf2f(p.w >> 16),     accb[7]);
    }
  }

  // reduce across the 16 edge slots (lane bits 2..5); partners share j.
  // accb partners stay within the j==0 lane group (bits 0..1 untouched).
#pragma unroll
  for (int c = 0; c < 8; ++c) { acc[c] += __shfl_xor(acc[c], 4);  accb[c] += __shfl_xor(accb[c], 4); }
#pragma unroll
  for (int c = 0; c < 8; ++c) { acc[c] += __shfl_xor(acc[c], 8);  accb[c] += __shfl_xor(accb[c], 8); }
#pragma unroll
  for (int c = 0; c < 8; ++c) { acc[c] += __shfl_xor(acc[c], 16); accb[c] += __shfl_xor(accb[c], 16); }
#pragma unroll
  for (int c = 0; c < 8; ++c) { acc[c] += __shfl_xor(acc[c], 32); accb[c] += __shfl_xor(accb[c], 32); }

  if (out_f32) {                    // out [N][40] f32
    if (lane < 4) {                 // j=0..3 -> cols 8j..8j+7
      float4 o0 = {acc[0], acc[1], acc[2], acc[3]};
      float4 o1 = {acc[4], acc[5], acc[6], acc[7]};
      float* p = zf + (size_t)node * C_DIM + j * 8;
      *(float4*)(p + 0) = o0;
      *(float4*)(p + 4) = o1;
    }
    if (lane == 0) {                // cols 32..39
      float4 o0 = {accb[0], accb[1], accb[2], accb[3]};
      float4 o1 = {accb[4], accb[5], accb[6], accb[7]};
      float* p = zf + (size_t)node * C_DIM + 32;
      *(float4*)(p + 0) = o0;
      *(float4*)(p + 4) = o1;
    }
  } else {                          // split bf16 layout
    if (lane < 4) {
      uint4 p;
      p.x = (uint)f2bf(acc[0]) | ((uint)f2bf(acc[1]) << 16);
      p.y = (uint)f2bf(acc[2]) | ((uint)f2bf(acc[3]) << 16);
      p.z = (uint)f2bf(acc[4]) | ((uint)f2bf(acc[5]) << 16);
      p.w = (uint)f2bf(acc[6]) | ((uint)f2bf(acc[7]) << 16);
      *(uint4*)(za + (size_t)node * XA_C + j * 8) = p;
    }
    if (lane == 0) {
      uint4 p;
      p.x = (uint)f2bf(accb[0]) | ((uint)f2bf(accb[1]) << 16);
      p.y = (uint)f2bf(accb[2]) | ((uint)f2bf(accb[3]) << 16);
      p.z = (uint)f2bf(accb[4]) | ((uint)f2bf(accb[5]) << 16);
      p.w = (uint)f2bf(accb[6]) | ((uint)f2bf(accb[7]) << 16);
      *(uint4*)(zb8 + (size_t)node * XB_C) = p;
    }
  }
}

// ---------------------------------------------------------------------------
extern "C" void kernel_launch(void* const* d_in, const int* in_sizes, int n_in,
                              void* d_out, int out_size, void* d_ws, size_t ws_size,
                              hipStream_t stream) {
  const float* feat  = (const float*)d_in[0];
  const float* W1    = (const float*)d_in[1];
  const float* W2    = (const float*)d_in[2];
  const int*   esrc  = (const int*)d_in[3];
  const int*   edst  = (const int*)d_in[4];
  const float* evalp = (const float*)d_in[5];
  float* out = (float*)d_out;

  const int N = in_sizes[0] / IN_DIM;   // 100000
  const int E = in_sizes[3];            // 1600000

  const int nblk = (N + BM - 1) / BM;   // GEMM1 blocks

  // ws: z0a [N][32] | z0b [N][8] | z1a [N][32] | z1b [N][8] | b_frag | w2f | row_ptr
  char* ws = (char*)d_ws;
  ushort* z0a    = (ushort*)ws;
  ushort* z0b    = z0a + (size_t)N * XA_C;
  ushort* z1a    = z0b + (size_t)N * XB_C;
  ushort* z1b    = z1a + (size_t)N * XA_C;
  ushort* b_frag = z1b + (size_t)N * XB_C;
  ushort* w2f    = b_frag + 4 * 16 * STEP;
  int* row_ptr   = (int*)(w2f + 16 * STEP);

  const int setup_items = E + 4096 + 1024;
  setup_kernel<<<(setup_items + 255) / 256, 256, 0, stream>>>(
      edst, E, row_ptr, N, W1, W2, b_frag, w2f);
  fused_dense_kernel<<<nblk, 256, 0, stream>>>(feat, b_frag, w2f, z0a, z0b, N);
  spmm_kernel<<<(N + 3) / 4, 256, 0, stream>>>(row_ptr, esrc, evalp, z0a, z0b,
                                               z1a, z1b, nullptr, N, 0);
  spmm_kernel<<<(N + 3) / 4, 256, 0, stream>>>(row_ptr, esrc, evalp, z1a, z1b,
                                               nullptr, nullptr, out, N, 1);
}

// Round 11
// 267.927 us; speedup vs baseline: 1.2332x; 1.2332x over previous
//
#include <hip/hip_runtime.h>
#include <cstddef>
#include <cstdint>

#define IN_DIM 256
#define H_DIM  128
#define C_DIM  40
#define BM     128
#define LDQ    68    // ushort stride of quarter-slab rows (136 B; 2-bank spread)
#define XA_C   32    // split-x: xa cols -> 64-B rows, 64-B aligned, ONE line/gather
#define XB_C   8     // split-x: xb cols -> 16-B rows, 1.6 MB, L2-resident
#define STEP   512   // ushorts per ks slab of b_frag/w2f: 64 lanes x 8 bf16

typedef short bf16x8 __attribute__((ext_vector_type(8)));
typedef float f32x16 __attribute__((ext_vector_type(16)));
typedef uint  u32x4  __attribute__((ext_vector_type(4)));

__device__ __forceinline__ ushort f2bf(float f) {   // RNE fp32 -> bf16
  uint u = __builtin_bit_cast(uint, f);
  u += 0x7fffu + ((u >> 16) & 1u);
  return (ushort)(u >> 16);
}
__device__ __forceinline__ float bf2f(uint s) {     // low 16 bits -> f32
  uint u = s << 16;
  return __builtin_bit_cast(float, u);
}
// packed fp32x2 -> bf16x2 (HW cvt if available; manual RNE fallback)
__device__ __forceinline__ uint pack2bf(float a, float b) {
#if __has_builtin(__builtin_amdgcn_cvt_pk_bf16_f32)
  typedef __bf16 bf16v2 __attribute__((ext_vector_type(2)));
  bf16v2 r = __builtin_amdgcn_cvt_pk_bf16_f32(a, b);
  return __builtin_bit_cast(uint, r);
#else
  return (uint)f2bf(a) | ((uint)f2bf(b) << 16);
#endif
}

// ---------------------------------------------------------------------------
// Setup (one launch):
//  tid < E:     CSR row_ptr via boundary scan of sorted dst (coalesced O(E)).
//  next 4096:   W1 -> b_frag (MFMA B-fragment order for GEMM1).
//  next 1024:   W2 -> w2f   (MFMA B-fragment order for GEMM2, zero-pad n>=40).
// ---------------------------------------------------------------------------
__global__ void setup_kernel(const int* __restrict__ dst, int E,
                             int* __restrict__ row_ptr, int N,
                             const float* __restrict__ W1,
                             const float* __restrict__ W2,
                             ushort* __restrict__ b_frag,
                             ushort* __restrict__ w2f) {
  int tid = blockIdx.x * blockDim.x + threadIdx.x;
  if (tid < E) {
    int d1 = dst[tid];
    int d0 = (tid == 0) ? -1 : dst[tid - 1];
    for (int v = d0 + 1; v <= d1; ++v) row_ptr[v] = tid;
    if (tid == E - 1)
      for (int v = d1 + 1; v <= N; ++v) row_ptr[v] = E;
    return;
  }
  int u = tid - E;
  if (u < 4096) {                               // W1 -> b_frag fragment order
    int l = u & 63, ks = (u >> 6) & 15, tn = u >> 10;
    int n  = 32 * tn + (l & 31);
    int k0 = ks * 16 + ((l >> 5) << 3);
    ushort r[8];
#pragma unroll
    for (int j = 0; j < 8; ++j) r[j] = f2bf(W1[(k0 + j) * H_DIM + n]);
    *(uint4*)(b_frag + u * 8) = *(uint4*)r;
    return;
  }
  u -= 4096;
  if (u < 1024) {                               // W2 -> w2f fragment order
    int l = u & 63, kt = u >> 6;                // kt = kb*2 + tn
    int tn = kt & 1, kb = kt >> 1;
    int n  = 32 * tn + (l & 31);
    int k0 = kb * 16 + ((l >> 5) << 3);
    ushort r[8];
#pragma unroll
    for (int j = 0; j < 8; ++j)
      r[j] = (n < C_DIM) ? f2bf(W2[(k0 + j) * C_DIM + n]) : (ushort)0;
    *(uint4*)(w2f + u * 8) = *(uint4*)r;
  }
}

// ---------------------------------------------------------------------------
// Fused dense MLP -> split z0 (z0a [N][32] bf16 + z0b [N][8] bf16).
// R9 structure (quarter-slab, zero barriers, continuous staging issue);
// final store in the split layout required by spmm. (Unchanged from R10.)
// ---------------------------------------------------------------------------
__global__ __launch_bounds__(256, 4) void fused_dense_kernel(
    const float* __restrict__ feat, const ushort* __restrict__ b_frag,
    const ushort* __restrict__ w2f, ushort* __restrict__ z0a,
    ushort* __restrict__ z0b, int N) {
  __shared__ __align__(16) ushort smem[4 * 32 * LDQ];   // 17408 B

  const int t = threadIdx.x;
  const int w = t >> 6, l = t & 63;
  const int nb = blockIdx.x * BM;
  ushort* slab = smem + w * (32 * LDQ);          // this wave's private region

  const int sr = l >> 4;                          // staging row-in-group 0..3
  const int sc = l & 15;                          // staging col quad (16 B)

  f32x16 acc[4];
#pragma unroll
  for (int tn = 0; tn < 4; ++tn)
#pragma unroll
    for (int r = 0; r < 16; ++r) acc[tn][r] = 0.f;

  const ushort* bp = b_frag + l * 8;
  bf16x8 Bx[2][4];
#pragma unroll
  for (int tn = 0; tn < 4; ++tn)
    Bx[0][tn] = *(const bf16x8*)(bp + tn * (16 * STEP));

  const float* fbase = feat + (size_t)(nb + 32 * w) * IN_DIM + sc * 4;

  float4 pre[8];
#pragma unroll
  for (int c = 0; c < 8; ++c) {
    int grow = nb + 32 * w + 4 * c + sr;
    const float* p = fbase + (size_t)(4 * c + sr) * IN_DIM;
    if (grow >= N) p = feat + (size_t)(N - 1) * IN_DIM + sc * 4;
    pre[c] = *(const float4*)(p);
  }
#pragma unroll
  for (int c = 0; c < 8; ++c) {
    uint2 pk;
    pk.x = pack2bf(pre[c].x, pre[c].y);
    pk.y = pack2bf(pre[c].z, pre[c].w);
    *(uint2*)(slab + (4 * c + sr) * LDQ + sc * 4) = pk;
  }

  const ushort* Abase = slab + (l & 31) * LDQ + ((l >> 5) << 3);

#pragma unroll
  for (int q = 0; q < 4; ++q) {
#pragma unroll
    for (int ks = 0; ks < 4; ++ks) {
      const int gks = 4 * q + ks;
      const int c = gks & 1;
      if (gks < 15) {
#pragma unroll
        for (int tn = 0; tn < 4; ++tn)
          Bx[c ^ 1][tn] = *(const bf16x8*)(bp + tn * (16 * STEP) + (gks + 1) * STEP);
      }
      if (q < 3) {
#pragma unroll
        for (int d = 0; d < 2; ++d) {
          const int cc = 2 * ks + d;
          int grow = nb + 32 * w + 4 * cc + sr;
          const float* p = fbase + (size_t)(4 * cc + sr) * IN_DIM + (q + 1) * 64;
          if (grow >= N) p = feat + (size_t)(N - 1) * IN_DIM + sc * 4 + (q + 1) * 64;
          pre[cc] = *(const float4*)(p);
        }
      }
      bf16x8 af = *(const bf16x8*)(Abase + ks * 16);
#pragma unroll
      for (int tn = 0; tn < 4; ++tn)
        acc[tn] = __builtin_amdgcn_mfma_f32_32x32x16_bf16(af, Bx[c][tn], acc[tn], 0, 0, 0);
    }
    if (q < 3) {
#pragma unroll
      for (int c = 0; c < 8; ++c) {
        uint2 pk;
        pk.x = pack2bf(pre[c].x, pre[c].y);
        pk.y = pack2bf(pre[c].z, pre[c].w);
        *(uint2*)(slab + (4 * c + sr) * LDQ + sc * 4) = pk;
      }
    }
  }

  // ---- GEMM2 over two h-chunks reusing the quarter slab (zero barriers)
  f32x16 acc2[2];
#pragma unroll
  for (int tn = 0; tn < 2; ++tn)
#pragma unroll
    for (int r = 0; r < 16; ++r) acc2[tn][r] = 0.f;

  const ushort* Hbase = slab + (l & 31) * LDQ + ((l >> 5) << 3);
  const ushort* wp = w2f + l * 8;

#pragma unroll
  for (int hc = 0; hc < 2; ++hc) {
#pragma unroll
    for (int tn = 2 * hc; tn < 2 * hc + 2; ++tn) {
      int col = (tn - 2 * hc) * 32 + (l & 31);
#pragma unroll
      for (int r = 0; r < 16; ++r) {
        int nl = (r & 3) + 8 * (r >> 2) + 4 * (l >> 5);
        float v = acc[tn][r];
        slab[nl * LDQ + col] = f2bf(v > 0.f ? v : 0.f);
      }
    }
#pragma unroll
    for (int kb = 4 * hc; kb < 4 * hc + 4; ++kb) {
      bf16x8 af = *(const bf16x8*)(Hbase + (kb - 4 * hc) * 16);
#pragma unroll
      for (int tn = 0; tn < 2; ++tn) {
        bf16x8 bfr = *(const bf16x8*)(wp + (kb * 2 + tn) * STEP);
        acc2[tn] = __builtin_amdgcn_mfma_f32_32x32x16_bf16(af, bfr, acc2[tn], 0, 0, 0);
      }
    }
  }

  // ---- store split z0: cols 0..31 -> z0a, cols 32..39 -> z0b
#pragma unroll
  for (int r = 0; r < 16; ++r) {
    int node = nb + 32 * w + (r & 3) + 8 * (r >> 2) + 4 * (l >> 5);
    if (node < N) {
      z0a[(size_t)node * XA_C + (l & 31)] = f2bf(acc2[0][r]);
      if ((l & 31) < XB_C)
        z0b[(size_t)node * XB_C + (l & 31)] = f2bf(acc2[1][r]);
    }
  }
}

// ---------------------------------------------------------------------------
// SPMM (CSR, dst-sorted): TWO nodes per wave (half-wave each), 8 nodes/block.
// Half-wave lane lh = 8-slot x 4-quad map: h = lh>>2 (edge slot), j = lh&3
// (xa col quad). xa [N][32] bf16 = 64-B aligned rows -> ONE line per edge
// (R10's traffic halving) AND the 16-edge dual-chain main loop matches the
// avg degree 16 -> 2 independent all-lane gathers in flight (R7's MLP, which
// R10 lost -> 1.37 TB/s collapse). xb [N][8] (1.6 MB, L2-resident) via j==0
// lanes. Reduce: shfl_xor 4/8/16 (stays within the 32-lane half).
// ---------------------------------------------------------------------------
__global__ __launch_bounds__(256) void spmm_kernel(
    const int* __restrict__ row_ptr, const int* __restrict__ esrc,
    const float* __restrict__ eval, const ushort* __restrict__ xa,
    const ushort* __restrict__ xb, ushort* __restrict__ za,
    ushort* __restrict__ zb8, float* __restrict__ zf, int N, int out_f32) {
  int node = blockIdx.x * 8 + (threadIdx.x >> 5);   // half-wave -> node
  if (node >= N) return;
  const int lh = threadIdx.x & 31;
  const int h = lh >> 2;            // edge slot 0..7
  const int j = lh & 3;             // col quad: xa cols 8j..8j+7

  int e   = row_ptr[node];
  int end = row_ptr[node + 1];

  float acc[8], accb[8];
#pragma unroll
  for (int c = 0; c < 8; ++c) { acc[c] = 0.f; accb[c] = 0.f; }

  // 16 edges per iteration: two independent 8-edge gather chains
  for (; e + 16 <= end; e += 16) {
    int   s0 = esrc[e + h];
    int   s1 = esrc[e + 8 + h];
    float v0 = eval[e + h];
    float v1 = eval[e + 8 + h];
    u32x4 a = *(const u32x4*)(xa + (size_t)s0 * XA_C + j * 8);
    u32x4 b = *(const u32x4*)(xa + (size_t)s1 * XA_C + j * 8);
    acc[0] = fmaf(v0, bf2f(a.x & 0xffffu), acc[0]);
    acc[1] = fmaf(v0, bf2f(a.x >> 16),     acc[1]);
    acc[2] = fmaf(v0, bf2f(a.y & 0xffffu), acc[2]);
    acc[3] = fmaf(v0, bf2f(a.y >> 16),     acc[3]);
    acc[4] = fmaf(v0, bf2f(a.z & 0xffffu), acc[4]);
    acc[5] = fmaf(v0, bf2f(a.z >> 16),     acc[5]);
    acc[6] = fmaf(v0, bf2f(a.w & 0xffffu), acc[6]);
    acc[7] = fmaf(v0, bf2f(a.w >> 16),     acc[7]);
    acc[0] = fmaf(v1, bf2f(b.x & 0xffffu), acc[0]);
    acc[1] = fmaf(v1, bf2f(b.x >> 16),     acc[1]);
    acc[2] = fmaf(v1, bf2f(b.y & 0xffffu), acc[2]);
    acc[3] = fmaf(v1, bf2f(b.y >> 16),     acc[3]);
    acc[4] = fmaf(v1, bf2f(b.z & 0xffffu), acc[4]);
    acc[5] = fmaf(v1, bf2f(b.z >> 16),     acc[5]);
    acc[6] = fmaf(v1, bf2f(b.w & 0xffffu), acc[6]);
    acc[7] = fmaf(v1, bf2f(b.w >> 16),     acc[7]);
    if (j == 0) {
      u32x4 p = *(const u32x4*)(xb + (size_t)s0 * XB_C);
      u32x4 q = *(const u32x4*)(xb + (size_t)s1 * XB_C);
      accb[0] = fmaf(v0, bf2f(p.x & 0xffffu), accb[0]);
      accb[1] = fmaf(v0, bf2f(p.x >> 16),     accb[1]);
      accb[2] = fmaf(v0, bf2f(p.y & 0xffffu), accb[2]);
      accb[3] = fmaf(v0, bf2f(p.y >> 16),     accb[3]);
      accb[4] = fmaf(v0, bf2f(p.z & 0xffffu), accb[4]);
      accb[5] = fmaf(v0, bf2f(p.z >> 16),     accb[5]);
      accb[6] = fmaf(v0, bf2f(p.w & 0xffffu), accb[6]);
      accb[7] = fmaf(v0, bf2f(p.w >> 16),     accb[7]);
      accb[0] = fmaf(v1, bf2f(q.x & 0xffffu), accb[0]);
      accb[1] = fmaf(v1, bf2f(q.x >> 16),     accb[1]);
      accb[2] = fmaf(v1, bf2f(q.y & 0xffffu), accb[2]);
      accb[3] = fmaf(v1, bf2f(q.y >> 16),     accb[3]);
      accb[4] = fmaf(v1, bf2f(q.z & 0xffffu), accb[4]);
      accb[5] = fmaf(v1, bf2f(q.z >> 16),     accb[5]);
      accb[6] = fmaf(v1, bf2f(q.w & 0xffffu), accb[6]);
      accb[7] = fmaf(v1, bf2f(q.w >> 16),     accb[7]);
    }
  }
  for (; e + 8 <= end; e += 8) {
    int   s = esrc[e + h];
    float v = eval[e + h];
    u32x4 a = *(const u32x4*)(xa + (size_t)s * XA_C + j * 8);
    acc[0] = fmaf(v, bf2f(a.x & 0xffffu), acc[0]);
    acc[1] = fmaf(v, bf2f(a.x >> 16),     acc[1]);
    acc[2] = fmaf(v, bf2f(a.y & 0xffffu), acc[2]);
    acc[3] = fmaf(v, bf2f(a.y >> 16),     acc[3]);
    acc[4] = fmaf(v, bf2f(a.z & 0xffffu), acc[4]);
    acc[5] = fmaf(v, bf2f(a.z >> 16),     acc[5]);
    acc[6] = fmaf(v, bf2f(a.w & 0xffffu), acc[6]);
    acc[7] = fmaf(v, bf2f(a.w >> 16),     acc[7]);
    if (j == 0) {
      u32x4 p = *(const u32x4*)(xb + (size_t)s * XB_C);
      accb[0] = fmaf(v, bf2f(p.x & 0xffffu), accb[0]);
      accb[1] = fmaf(v, bf2f(p.x >> 16),     accb[1]);
      accb[2] = fmaf(v, bf2f(p.y & 0xffffu), accb[2]);
      accb[3] = fmaf(v, bf2f(p.y >> 16),     accb[3]);
      accb[4] = fmaf(v, bf2f(p.z & 0xffffu), accb[4]);
      accb[5] = fmaf(v, bf2f(p.z >> 16),     accb[5]);
      accb[6] = fmaf(v, bf2f(p.w & 0xffffu), accb[6]);
      accb[7] = fmaf(v, bf2f(p.w >> 16),     accb[7]);
    }
  }
  if (e < end) {                    // tail: clamp slots past the end, weight 0
    int ei = e + h;
    int ec = ei < end ? ei : end - 1;
    int   s  = esrc[ec];
    float v0 = eval[ec];
    float v  = ei < end ? v0 : 0.f;
    u32x4 a = *(const u32x4*)(xa + (size_t)s * XA_C + j * 8);
    acc[0] = fmaf(v, bf2f(a.x & 0xffffu), acc[0]);
    acc[1] = fmaf(v, bf2f(a.x >> 16),     acc[1]);
    acc[2] = fmaf(v, bf2f(a.y & 0xffffu), acc[2]);
    acc[3] = fmaf(v, bf2f(a.y >> 16),     acc[3]);
    acc[4] = fmaf(v, bf2f(a.z & 0xffffu), acc[4]);
    acc[5] = fmaf(v, bf2f(a.z >> 16),     acc[5]);
    acc[6] = fmaf(v, bf2f(a.w & 0xffffu), acc[6]);
    acc[7] = fmaf(v, bf2f(a.w >> 16),     acc[7]);
    if (j == 0) {
      u32x4 p = *(const u32x4*)(xb + (size_t)s * XB_C);
      accb[0] = fmaf(v, bf2f(p.x & 0xffffu), accb[0]);
      accb[1] = fmaf(v, bf2f(p.x >> 16),     accb[1]);
      accb[2] = fmaf(v, bf2f(p.y & 0xffffu), accb[2]);
      accb[3] = fmaf(v, bf2f(p.y >> 16),     accb[3]);
      accb[4] = fmaf(v, bf2f(p.z & 0xffffu), accb[4]);
      accb[5] = fmaf(v, bf2f(p.z >> 16),     accb[5]);
      accb[6] = fmaf(v, bf2f(p.w & 0xffffu), accb[6]);
      accb[7] = fmaf(v, bf2f(p.w >> 16),     accb[7]);
    }
  }

  // reduce across the 8 edge slots (lane bits 2..4); partners share j and half
#pragma unroll
  for (int c = 0; c < 8; ++c) { acc[c] += __shfl_xor(acc[c], 4);  accb[c] += __shfl_xor(accb[c], 4); }
#pragma unroll
  for (int c = 0; c < 8; ++c) { acc[c] += __shfl_xor(acc[c], 8);  accb[c] += __shfl_xor(accb[c], 8); }
#pragma unroll
  for (int c = 0; c < 8; ++c) { acc[c] += __shfl_xor(acc[c], 16); accb[c] += __shfl_xor(accb[c], 16); }

  if (out_f32) {                    // out [N][40] f32
    if (h == 0) {                   // j=0..3 -> cols 8j..8j+7
      float4 o0 = {acc[0], acc[1], acc[2], acc[3]};
      float4 o1 = {acc[4], acc[5], acc[6], acc[7]};
      float* p = zf + (size_t)node * C_DIM + j * 8;
      *(float4*)(p + 0) = o0;
      *(float4*)(p + 4) = o1;
      if (j == 0) {                 // cols 32..39
        float4 b0 = {accb[0], accb[1], accb[2], accb[3]};
        float4 b1 = {accb[4], accb[5], accb[6], accb[7]};
        float* pb = zf + (size_t)node * C_DIM + 32;
        *(float4*)(pb + 0) = b0;
        *(float4*)(pb + 4) = b1;
      }
    }
  } else {                          // split bf16 layout
    if (h == 0) {
      uint4 p;
      p.x = (uint)f2bf(acc[0]) | ((uint)f2bf(acc[1]) << 16);
      p.y = (uint)f2bf(acc[2]) | ((uint)f2bf(acc[3]) << 16);
      p.z = (uint)f2bf(acc[4]) | ((uint)f2bf(acc[5]) << 16);
      p.w = (uint)f2bf(acc[6]) | ((uint)f2bf(acc[7]) << 16);
      *(uint4*)(za + (size_t)node * XA_C + j * 8) = p;
      if (j == 0) {
        uint4 q;
        q.x = (uint)f2bf(accb[0]) | ((uint)f2bf(accb[1]) << 16);
        q.y = (uint)f2bf(accb[2]) | ((uint)f2bf(accb[3]) << 16);
        q.z = (uint)f2bf(accb[4]) | ((uint)f2bf(accb[5]) << 16);
        q.w = (uint)f2bf(accb[6]) | ((uint)f2bf(accb[7]) << 16);
        *(uint4*)(zb8 + (size_t)node * XB_C) = q;
      }
    }
  }
}

// ---------------------------------------------------------------------------
extern "C" void kernel_launch(void* const* d_in, const int* in_sizes, int n_in,
                              void* d_out, int out_size, void* d_ws, size_t ws_size,
                              hipStream_t stream) {
  const float* feat  = (const float*)d_in[0];
  const float* W1    = (const float*)d_in[1];
  const float* W2    = (const float*)d_in[2];
  const int*   esrc  = (const int*)d_in[3];
  const int*   edst  = (const int*)d_in[4];
  const float* evalp = (const float*)d_in[5];
  float* out = (float*)d_out;

  const int N = in_sizes[0] / IN_DIM;   // 100000
  const int E = in_sizes[3];            // 1600000

  const int nblk = (N + BM - 1) / BM;   // GEMM1 blocks

  // ws: z0a [N][32] | z0b [N][8] | z1a [N][32] | z1b [N][8] | b_frag | w2f | row_ptr
  char* ws = (char*)d_ws;
  ushort* z0a    = (ushort*)ws;
  ushort* z0b    = z0a + (size_t)N * XA_C;
  ushort* z1a    = z0b + (size_t)N * XB_C;
  ushort* z1b    = z1a + (size_t)N * XA_C;
  ushort* b_frag = z1b + (size_t)N * XB_C;
  ushort* w2f    = b_frag + 4 * 16 * STEP;
  int* row_ptr   = (int*)(w2f + 16 * STEP);

  const int setup_items = E + 4096 + 1024;
  setup_kernel<<<(setup_items + 255) / 256, 256, 0, stream>>>(
      edst, E, row_ptr, N, W1, W2, b_frag, w2f);
  fused_dense_kernel<<<nblk, 256, 0, stream>>>(feat, b_frag, w2f, z0a, z0b, N);
  spmm_kernel<<<(N + 7) / 8, 256, 0, stream>>>(row_ptr, esrc, evalp, z0a, z0b,
                                               z1a, z1b, nullptr, N, 0);
  spmm_kernel<<<(N + 7) / 8, 256, 0, stream>>>(row_ptr, esrc, evalp, z1a, z1b,
                                               nullptr, nullptr, out, N, 1);
}

// Round 12
// 267.887 us; speedup vs baseline: 1.2334x; 1.0002x over previous
//
#include <hip/hip_runtime.h>
#include <cstddef>
#include <cstdint>

#define IN_DIM 256
#define H_DIM  128
#define C_DIM  40
#define BM     128
#define LDQ    68     // ushort stride of quarter-slab rows (136 B)
#define XA_C   32     // split-x: xa cols -> 64-B rows, 64-B aligned, ONE line/gather
#define XB_C   8      // split-x: xb cols -> 16-B rows, 1.6 MB, L2-resident
#define STEP   512    // ushorts per fragment slab: 64 lanes x 8 bf16
#define B_OFF  (4 * 32 * LDQ)      // 8704  ushorts: B half-tile region
#define W2_OFF (B_OFF + 16384)     // 25088 ushorts: W2 region
// smem total = 25088 + 8192 = 33280 ushorts = 66560 B -> 2 blocks/CU

typedef short bf16x8 __attribute__((ext_vector_type(8)));
typedef float f32x16 __attribute__((ext_vector_type(16)));
typedef uint  u32x4  __attribute__((ext_vector_type(4)));

__device__ __forceinline__ ushort f2bf(float f) {   // RNE fp32 -> bf16
  uint u = __builtin_bit_cast(uint, f);
  u += 0x7fffu + ((u >> 16) & 1u);
  return (ushort)(u >> 16);
}
__device__ __forceinline__ float bf2f(uint s) {     // low 16 bits -> f32
  uint u = s << 16;
  return __builtin_bit_cast(float, u);
}
// packed fp32x2 -> bf16x2 (HW cvt if available; manual RNE fallback)
__device__ __forceinline__ uint pack2bf(float a, float b) {
#if __has_builtin(__builtin_amdgcn_cvt_pk_bf16_f32)
  typedef __bf16 bf16v2 __attribute__((ext_vector_type(2)));
  bf16v2 r = __builtin_amdgcn_cvt_pk_bf16_f32(a, b);
  return __builtin_bit_cast(uint, r);
#else
  return (uint)f2bf(a) | ((uint)f2bf(b) << 16);
#endif
}

// ---------------------------------------------------------------------------
// Setup (one launch):
//  tid < E:     CSR row_ptr via boundary scan of sorted dst (coalesced O(E)).
//  next 4096:   W1 -> b_frag, KS-MAJOR fragment order (for LDS half staging):
//               b_frag[(ks*4+tn)*512 + l*8 ..] = W1[16ks+(l>>5)*8+j][32tn+(l&31)]
//  next 1024:   W2 -> w2f (fragment order, kt = kb*2+tn major, zero-pad n>=40).
// ---------------------------------------------------------------------------
__global__ void setup_kernel(const int* __restrict__ dst, int E,
                             int* __restrict__ row_ptr, int N,
                             const float* __restrict__ W1,
                             const float* __restrict__ W2,
                             ushort* __restrict__ b_frag,
                             ushort* __restrict__ w2f) {
  int tid = blockIdx.x * blockDim.x + threadIdx.x;
  if (tid < E) {
    int d1 = dst[tid];
    int d0 = (tid == 0) ? -1 : dst[tid - 1];
    for (int v = d0 + 1; v <= d1; ++v) row_ptr[v] = tid;
    if (tid == E - 1)
      for (int v = d1 + 1; v <= N; ++v) row_ptr[v] = E;
    return;
  }
  int u = tid - E;
  if (u < 4096) {                               // W1 -> b_frag (ks-major)
    int l = u & 63, tn = (u >> 6) & 3, ks = u >> 8;
    int n  = 32 * tn + (l & 31);
    int k0 = ks * 16 + ((l >> 5) << 3);
    ushort r[8];
#pragma unroll
    for (int j = 0; j < 8; ++j) r[j] = f2bf(W1[(k0 + j) * H_DIM + n]);
    *(uint4*)(b_frag + u * 8) = *(uint4*)r;
    return;
  }
  u -= 4096;
  if (u < 1024) {                               // W2 -> w2f fragment order
    int l = u & 63, kt = u >> 6;                // kt = kb*2 + tn
    int tn = kt & 1, kb = kt >> 1;
    int n  = 32 * tn + (l & 31);
    int k0 = kb * 16 + ((l >> 5) << 3);
    ushort r[8];
#pragma unroll
    for (int j = 0; j < 8; ++j)
      r[j] = (n < C_DIM) ? f2bf(W2[(k0 + j) * C_DIM + n]) : (ushort)0;
    *(uint4*)(w2f + u * 8) = *(uint4*)r;
  }
}

// ---------------------------------------------------------------------------
// Fused dense MLP -> split z0 (z0a [N][32] bf16 + z0b [N][8] bf16).
// R12 fix for the 58-us wall: previous versions kept B (32 VGPR ping-pong) +
// pre[8] (32 VGPR) + acc (64) live -> VGPR_Count 64-88 => spill/AGPR churn,
// serializing every load->use chain (measured ~47K cy/block-round == sum of
// serialized load latencies; MfmaUtil 5%, VALUBusy 8%, HBM 12% all idle).
// Now: B and W2 live in BLOCK-SHARED LDS (staged 32 KB/half + 16 KB once);
// K-loop operands are ds_read_b128 (lgkmcnt, decoupled from staging vmcnt).
// Per-wave VMEM = 32 grouped A-staging loads (1 counted wait/quarter) + 12
// stage-copy loads. 3 barriers total. LDS 66.6 KB -> 2 blocks/CU, 8 waves/CU.
// ---------------------------------------------------------------------------
__global__ __launch_bounds__(256, 2) void fused_dense_kernel(
    const float* __restrict__ feat, const ushort* __restrict__ b_frag,
    const ushort* __restrict__ w2f, ushort* __restrict__ z0a,
    ushort* __restrict__ z0b, int N) {
  __shared__ __align__(16) ushort smem[33280];

  const int t = threadIdx.x;
  const int w = t >> 6, l = t & 63;
  const int nb = blockIdx.x * BM;
  ushort* slab = smem + w * (32 * LDQ);          // wave-private A/h slab

  const int sr = l >> 4;                          // staging row-in-group 0..3
  const int sc = l & 15;                          // staging col quad (16 B)

  f32x16 acc[4];
#pragma unroll
  for (int tn = 0; tn < 4; ++tn)
#pragma unroll
    for (int r = 0; r < 16; ++r) acc[tn][r] = 0.f;

  // ---- stage B half0 (32 KB) + W2 (16 KB) into shared LDS
#pragma unroll
  for (int i = 0; i < 8; ++i)
    *(uint4*)(smem + B_OFF + t * 64 + i * 8) =
        *(const uint4*)(b_frag + t * 64 + i * 8);
#pragma unroll
  for (int i = 0; i < 4; ++i)
    *(uint4*)(smem + W2_OFF + t * 32 + i * 8) =
        *(const uint4*)(w2f + t * 32 + i * 8);

  // ---- A quarter 0: grouped loads -> pack -> wave-private LDS; prefetch q1
  const float* fbase = feat + (size_t)(nb + 32 * w) * IN_DIM + sc * 4;
  float4 pre[8];
#pragma unroll
  for (int c = 0; c < 8; ++c) {
    int grow = nb + 32 * w + 4 * c + sr;
    const float* p = fbase + (size_t)(4 * c + sr) * IN_DIM;
    if (grow >= N) p = feat + (size_t)(N - 1) * IN_DIM + sc * 4;
    pre[c] = *(const float4*)(p);
  }
#pragma unroll
  for (int c = 0; c < 8; ++c) {
    uint2 pk;
    pk.x = pack2bf(pre[c].x, pre[c].y);
    pk.y = pack2bf(pre[c].z, pre[c].w);
    *(uint2*)(slab + (4 * c + sr) * LDQ + sc * 4) = pk;
  }
#pragma unroll
  for (int c = 0; c < 8; ++c) {                   // prefetch quarter 1
    int grow = nb + 32 * w + 4 * c + sr;
    const float* p = fbase + (size_t)(4 * c + sr) * IN_DIM + 64;
    if (grow >= N) p = feat + (size_t)(N - 1) * IN_DIM + sc * 4 + 64;
    pre[c] = *(const float4*)(p);
  }
  __syncthreads();                                // B half0 + W2 visible

  const ushort* Abase = slab + (l & 31) * LDQ + ((l >> 5) << 3);

#pragma unroll
  for (int q = 0; q < 4; ++q) {
    if (q == 2) {                                 // swap B halves (shared)
      __syncthreads();                            // all waves done with half0
#pragma unroll
      for (int i = 0; i < 8; ++i)
        *(uint4*)(smem + B_OFF + t * 64 + i * 8) =
            *(const uint4*)(b_frag + 16384 + t * 64 + i * 8);
      __syncthreads();                            // half1 visible
    }
#pragma unroll
    for (int ksl = 0; ksl < 4; ++ksl) {
      const int gks = 4 * q + ksl;
      bf16x8 af = *(const bf16x8*)(Abase + ksl * 16);
#pragma unroll
      for (int tn = 0; tn < 4; ++tn) {
        bf16x8 bfr = *(const bf16x8*)(smem + B_OFF + ((gks & 7) * 256 + tn * 64 + l) * 8);
        acc[tn] = __builtin_amdgcn_mfma_f32_32x32x16_bf16(af, bfr, acc[tn], 0, 0, 0);
      }
    }
    if (q < 3) {                                  // write A q+1; prefetch q+2
#pragma unroll
      for (int c = 0; c < 8; ++c) {
        uint2 pk;
        pk.x = pack2bf(pre[c].x, pre[c].y);
        pk.y = pack2bf(pre[c].z, pre[c].w);
        *(uint2*)(slab + (4 * c + sr) * LDQ + sc * 4) = pk;
      }
      if (q < 2) {
#pragma unroll
        for (int c = 0; c < 8; ++c) {
          int grow = nb + 32 * w + 4 * c + sr;
          const float* p = fbase + (size_t)(4 * c + sr) * IN_DIM + (q + 2) * 64;
          if (grow >= N) p = feat + (size_t)(N - 1) * IN_DIM + sc * 4 + (q + 2) * 64;
          pre[c] = *(const float4*)(p);
        }
      }
    }
  }

  // ---- GEMM2 over two h-chunks reusing the wave slab; W2 from shared LDS
  f32x16 acc2[2];
#pragma unroll
  for (int tn = 0; tn < 2; ++tn)
#pragma unroll
    for (int r = 0; r < 16; ++r) acc2[tn][r] = 0.f;

#pragma unroll
  for (int hc = 0; hc < 2; ++hc) {
#pragma unroll
    for (int tn = 2 * hc; tn < 2 * hc + 2; ++tn) {
      int col = (tn - 2 * hc) * 32 + (l & 31);
#pragma unroll
      for (int r = 0; r < 16; ++r) {
        int nl = (r & 3) + 8 * (r >> 2) + 4 * (l >> 5);
        float v = acc[tn][r];
        slab[nl * LDQ + col] = f2bf(v > 0.f ? v : 0.f);
      }
    }
#pragma unroll
    for (int kb = 4 * hc; kb < 4 * hc + 4; ++kb) {
      bf16x8 af = *(const bf16x8*)(Abase + (kb - 4 * hc) * 16);
#pragma unroll
      for (int tn = 0; tn < 2; ++tn) {
        bf16x8 bfr = *(const bf16x8*)(smem + W2_OFF + (kb * 2 + tn) * 512 + l * 8);
        acc2[tn] = __builtin_amdgcn_mfma_f32_32x32x16_bf16(af, bfr, acc2[tn], 0, 0, 0);
      }
    }
  }

  // ---- store split z0: cols 0..31 -> z0a, cols 32..39 -> z0b
#pragma unroll
  for (int r = 0; r < 16; ++r) {
    int node = nb + 32 * w + (r & 3) + 8 * (r >> 2) + 4 * (l >> 5);
    if (node < N) {
      z0a[(size_t)node * XA_C + (l & 31)] = f2bf(acc2[0][r]);
      if ((l & 31) < XB_C)
        z0b[(size_t)node * XB_C + (l & 31)] = f2bf(acc2[1][r]);
    }
  }
}

// ---------------------------------------------------------------------------
// SPMM (CSR, dst-sorted): TWO nodes per wave (half-wave each), 8 nodes/block.
// xa [N][32] bf16 = 64-B aligned rows -> ONE line per edge; 16-edge dual-chain
// main loop matches avg degree 16. xb via j==0 lanes. (R11 form, unchanged.)
// ---------------------------------------------------------------------------
__global__ __launch_bounds__(256) void spmm_kernel(
    const int* __restrict__ row_ptr, const int* __restrict__ esrc,
    const float* __restrict__ eval, const ushort* __restrict__ xa,
    const ushort* __restrict__ xb, ushort* __restrict__ za,
    ushort* __restrict__ zb8, float* __restrict__ zf, int N, int out_f32) {
  int node = blockIdx.x * 8 + (threadIdx.x >> 5);   // half-wave -> node
  if (node >= N) return;
  const int lh = threadIdx.x & 31;
  const int h = lh >> 2;            // edge slot 0..7
  const int j = lh & 3;             // col quad: xa cols 8j..8j+7

  int e   = row_ptr[node];
  int end = row_ptr[node + 1];

  float acc[8], accb[8];
#pragma unroll
  for (int c = 0; c < 8; ++c) { acc[c] = 0.f; accb[c] = 0.f; }

  // 16 edges per iteration: two independent 8-edge gather chains
  for (; e + 16 <= end; e += 16) {
    int   s0 = esrc[e + h];
    int   s1 = esrc[e + 8 + h];
    float v0 = eval[e + h];
    float v1 = eval[e + 8 + h];
    u32x4 a = *(const u32x4*)(xa + (size_t)s0 * XA_C + j * 8);
    u32x4 b = *(const u32x4*)(xa + (size_t)s1 * XA_C + j * 8);
    acc[0] = fmaf(v0, bf2f(a.x & 0xffffu), acc[0]);
    acc[1] = fmaf(v0, bf2f(a.x >> 16),     acc[1]);
    acc[2] = fmaf(v0, bf2f(a.y & 0xffffu), acc[2]);
    acc[3] = fmaf(v0, bf2f(a.y >> 16),     acc[3]);
    acc[4] = fmaf(v0, bf2f(a.z & 0xffffu), acc[4]);
    acc[5] = fmaf(v0, bf2f(a.z >> 16),     acc[5]);
    acc[6] = fmaf(v0, bf2f(a.w & 0xffffu), acc[6]);
    acc[7] = fmaf(v0, bf2f(a.w >> 16),     acc[7]);
    acc[0] = fmaf(v1, bf2f(b.x & 0xffffu), acc[0]);
    acc[1] = fmaf(v1, bf2f(b.x >> 16),     acc[1]);
    acc[2] = fmaf(v1, bf2f(b.y & 0xffffu), acc[2]);
    acc[3] = fmaf(v1, bf2f(b.y >> 16),     acc[3]);
    acc[4] = fmaf(v1, bf2f(b.z & 0xffffu), acc[4]);
    acc[5] = fmaf(v1, bf2f(b.z >> 16),     acc[5]);
    acc[6] = fmaf(v1, bf2f(b.w & 0xffffu), acc[6]);
    acc[7] = fmaf(v1, bf2f(b.w >> 16),     acc[7]);
    if (j == 0) {
      u32x4 p = *(const u32x4*)(xb + (size_t)s0 * XB_C);
      u32x4 q = *(const u32x4*)(xb + (size_t)s1 * XB_C);
      accb[0] = fmaf(v0, bf2f(p.x & 0xffffu), accb[0]);
      accb[1] = fmaf(v0, bf2f(p.x >> 16),     accb[1]);
      accb[2] = fmaf(v0, bf2f(p.y & 0xffffu), accb[2]);
      accb[3] = fmaf(v0, bf2f(p.y >> 16),     accb[3]);
      accb[4] = fmaf(v0, bf2f(p.z & 0xffffu), accb[4]);
      accb[5] = fmaf(v0, bf2f(p.z >> 16),     accb[5]);
      accb[6] = fmaf(v0, bf2f(p.w & 0xffffu), accb[6]);
      accb[7] = fmaf(v0, bf2f(p.w >> 16),     accb[7]);
      accb[0] = fmaf(v1, bf2f(q.x & 0xffffu), accb[0]);
      accb[1] = fmaf(v1, bf2f(q.x >> 16),     accb[1]);
      accb[2] = fmaf(v1, bf2f(q.y & 0xffffu), accb[2]);
      accb[3] = fmaf(v1, bf2f(q.y >> 16),     accb[3]);
      accb[4] = fmaf(v1, bf2f(q.z & 0xffffu), accb[4]);
      accb[5] = fmaf(v1, bf2f(q.z >> 16),     accb[5]);
      accb[6] = fmaf(v1, bf2f(q.w & 0xffffu), accb[6]);
      accb[7] = fmaf(v1, bf2f(q.w >> 16),     accb[7]);
    }
  }
  for (; e + 8 <= end; e += 8) {
    int   s = esrc[e + h];
    float v = eval[e + h];
    u32x4 a = *(const u32x4*)(xa + (size_t)s * XA_C + j * 8);
    acc[0] = fmaf(v, bf2f(a.x & 0xffffu), acc[0]);
    acc[1] = fmaf(v, bf2f(a.x >> 16),     acc[1]);
    acc[2] = fmaf(v, bf2f(a.y & 0xffffu), acc[2]);
    acc[3] = fmaf(v, bf2f(a.y >> 16),     acc[3]);
    acc[4] = fmaf(v, bf2f(a.z & 0xffffu), acc[4]);
    acc[5] = fmaf(v, bf2f(a.z >> 16),     acc[5]);
    acc[6] = fmaf(v, bf2f(a.w & 0xffffu), acc[6]);
    acc[7] = fmaf(v, bf2f(a.w >> 16),     acc[7]);
    if (j == 0) {
      u32x4 p = *(const u32x4*)(xb + (size_t)s * XB_C);
      accb[0] = fmaf(v, bf2f(p.x & 0xffffu), accb[0]);
      accb[1] = fmaf(v, bf2f(p.x >> 16),     accb[1]);
      accb[2] = fmaf(v, bf2f(p.y & 0xffffu), accb[2]);
      accb[3] = fmaf(v, bf2f(p.y >> 16),     accb[3]);
      accb[4] = fmaf(v, bf2f(p.z & 0xffffu), accb[4]);
      accb[5] = fmaf(v, bf2f(p.z >> 16),     accb[5]);
      accb[6] = fmaf(v, bf2f(p.w & 0xffffu), accb[6]);
      accb[7] = fmaf(v, bf2f(p.w >> 16),     accb[7]);
    }
  }
  if (e < end) {                    // tail: clamp slots past the end, weight 0
    int ei = e + h;
    int ec = ei < end ? ei : end - 1;
    int   s  = esrc[ec];
    float v0 = eval[ec];
    float v  = ei < end ? v0 : 0.f;
    u32x4 a = *(const u32x4*)(xa + (size_t)s * XA_C + j * 8);
    acc[0] = fmaf(v, bf2f(a.x & 0xffffu), acc[0]);
    acc[1] = fmaf(v, bf2f(a.x >> 16),     acc[1]);
    acc[2] = fmaf(v, bf2f(a.y & 0xffffu), acc[2]);
    acc[3] = fmaf(v, bf2f(a.y >> 16),     acc[3]);
    acc[4] = fmaf(v, bf2f(a.z & 0xffffu), acc[4]);
    acc[5] = fmaf(v, bf2f(a.z >> 16),     acc[5]);
    acc[6] = fmaf(v, bf2f(a.w & 0xffffu), acc[6]);
    acc[7] = fmaf(v, bf2f(a.w >> 16),     acc[7]);
    if (j == 0) {
      u32x4 p = *(const u32x4*)(xb + (size_t)s * XB_C);
      accb[0] = fmaf(v, bf2f(p.x & 0xffffu), accb[0]);
      accb[1] = fmaf(v, bf2f(p.x >> 16),     accb[1]);
      accb[2] = fmaf(v, bf2f(p.y & 0xffffu), accb[2]);
      accb[3] = fmaf(v, bf2f(p.y >> 16),     accb[3]);
      accb[4] = fmaf(v, bf2f(p.z & 0xffffu), accb[4]);
      accb[5] = fmaf(v, bf2f(p.z >> 16),     accb[5]);
      accb[6] = fmaf(v, bf2f(p.w & 0xffffu), accb[6]);
      accb[7] = fmaf(v, bf2f(p.w >> 16),     accb[7]);
    }
  }

  // reduce across the 8 edge slots (lane bits 2..4); partners share j and half
#pragma unroll
  for (int c = 0; c < 8; ++c) { acc[c] += __shfl_xor(acc[c], 4);  accb[c] += __shfl_xor(accb[c], 4); }
#pragma unroll
  for (int c = 0; c < 8; ++c) { acc[c] += __shfl_xor(acc[c], 8);  accb[c] += __shfl_xor(accb[c], 8); }
#pragma unroll
  for (int c = 0; c < 8; ++c) { acc[c] += __shfl_xor(acc[c], 16); accb[c] += __shfl_xor(accb[c], 16); }

  if (out_f32) {                    // out [N][40] f32
    if (h == 0) {                   // j=0..3 -> cols 8j..8j+7
      float4 o0 = {acc[0], acc[1], acc[2], acc[3]};
      float4 o1 = {acc[4], acc[5], acc[6], acc[7]};
      float* p = zf + (size_t)node * C_DIM + j * 8;
      *(float4*)(p + 0) = o0;
      *(float4*)(p + 4) = o1;
      if (j == 0) {                 // cols 32..39
        float4 b0 = {accb[0], accb[1], accb[2], accb[3]};
        float4 b1 = {accb[4], accb[5], accb[6], accb[7]};
        float* pb = zf + (size_t)node * C_DIM + 32;
        *(float4*)(pb + 0) = b0;
        *(float4*)(pb + 4) = b1;
      }
    }
  } else {                          // split bf16 layout
    if (h == 0) {
      uint4 p;
      p.x = (uint)f2bf(acc[0]) | ((uint)f2bf(acc[1]) << 16);
      p.y = (uint)f2bf(acc[2]) | ((uint)f2bf(acc[3]) << 16);
      p.z = (uint)f2bf(acc[4]) | ((uint)f2bf(acc[5]) << 16);
      p.w = (uint)f2bf(acc[6]) | ((uint)f2bf(acc[7]) << 16);
      *(uint4*)(za + (size_t)node * XA_C + j * 8) = p;
      if (j == 0) {
        uint4 q;
        q.x = (uint)f2bf(accb[0]) | ((uint)f2bf(accb[1]) << 16);
        q.y = (uint)f2bf(accb[2]) | ((uint)f2bf(accb[3]) << 16);
        q.z = (uint)f2bf(accb[4]) | ((uint)f2bf(accb[5]) << 16);
        q.w = (uint)f2bf(accb[6]) | ((uint)f2bf(accb[7]) << 16);
        *(uint4*)(zb8 + (size_t)node * XB_C) = q;
      }
    }
  }
}

// ---------------------------------------------------------------------------
extern "C" void kernel_launch(void* const* d_in, const int* in_sizes, int n_in,
                              void* d_out, int out_size, void* d_ws, size_t ws_size,
                              hipStream_t stream) {
  const float* feat  = (const float*)d_in[0];
  const float* W1    = (const float*)d_in[1];
  const float* W2    = (const float*)d_in[2];
  const int*   esrc  = (const int*)d_in[3];
  const int*   edst  = (const int*)d_in[4];
  const float* evalp = (const float*)d_in[5];
  float* out = (float*)d_out;

  const int N = in_sizes[0] / IN_DIM;   // 100000
  const int E = in_sizes[3];            // 1600000

  const int nblk = (N + BM - 1) / BM;   // GEMM1 blocks

  // ws: z0a [N][32] | z0b [N][8] | z1a [N][32] | z1b [N][8] | b_frag | w2f | row_ptr
  char* ws = (char*)d_ws;
  ushort* z0a    = (ushort*)ws;
  ushort* z0b    = z0a + (size_t)N * XA_C;
  ushort* z1a    = z0b + (size_t)N * XB_C;
  ushort* z1b    = z1a + (size_t)N * XA_C;
  ushort* b_frag = z1b + (size_t)N * XB_C;
  ushort* w2f    = b_frag + 4 * 16 * STEP;
  int* row_ptr   = (int*)(w2f + 16 * STEP);

  const int setup_items = E + 4096 + 1024;
  setup_kernel<<<(setup_items + 255) / 256, 256, 0, stream>>>(
      edst, E, row_ptr, N, W1, W2, b_frag, w2f);
  fused_dense_kernel<<<nblk, 256, 0, stream>>>(feat, b_frag, w2f, z0a, z0b, N);
  spmm_kernel<<<(N + 7) / 8, 256, 0, stream>>>(row_ptr, esrc, evalp, z0a, z0b,
                                               z1a, z1b, nullptr, N, 0);
  spmm_kernel<<<(N + 7) / 8, 256, 0, stream>>>(row_ptr, esrc, evalp, z1a, z1b,
                                               nullptr, nullptr, out, N, 1);
}